// Round 1
// 884.158 us; speedup vs baseline: 2.5962x; 2.5962x over previous
//
#include <hip/hip_runtime.h>

#define N_NODES 10000
#define IN_DIM 128
#define EDGE_DIM 64
#define HID_DIM 256
#define OUT_DIM 128
#define N_EDGES 640000

// Data contract (verified R6): fp32 buffers (values bf16-rounded), int32
// edge_index, fp32 output, atomic scatter into d_out.
// This round: GEMM2 moved from VALU to MFMA. W2 A-fragments register-resident
// (32 VGPRs, replaces 64-VGPR w2r). D -> sMsg (LDS, aliased over sMu) -> same
// coalesced scatter as before. m-staging vectorized to float4.

typedef __bf16 bf16x8 __attribute__((ext_vector_type(8)));
typedef float f32x4 __attribute__((ext_vector_type(4)));

static __device__ __forceinline__ unsigned short f2bf(float f) {
    unsigned u = __builtin_bit_cast(unsigned, f);
    u = (u + 0x7fffu + ((u >> 16) & 1u)) >> 16;   // RNE; finite inputs
    return (unsigned short)u;
}

__global__ void zero_kernel(float* __restrict__ out) {
    int t = blockIdx.x * 256 + threadIdx.x;
    if (t < 320000) ((float4*)out)[t] = make_float4(0.f, 0.f, 0.f, 0.f);
}

__global__ __launch_bounds__(256, 2) void gine_hybrid(
    const int* __restrict__ ei,
    const float* __restrict__ x,
    const float* __restrict__ ea,
    const float* __restrict__ W1,
    const float* __restrict__ b1,
    const float* __restrict__ W2,
    const float* __restrict__ b2,
    float* __restrict__ out)
{
    __shared__ unsigned        sW1u[128 * 97];    // 49,664 B: W1 half, bf16 pairs, +1 pad
    __shared__ __align__(16) float sMsg[16 * 132];// 8,448 B: msg f32 (aliases sMu in time)
    __shared__ unsigned short  sHu[16 * 132];     // 4,224 B: h (16 edges x 128 hid), bf16
    __shared__ float           sB1[128];
    __shared__ int             sSE[16], sDE[16];

    // sMu (m as bf16 pairs, stride 97 uints) time-shares sMsg's storage:
    // sMu is read only in GEMM1 (before the post-GEMM1 barrier); sMsg is
    // written only in GEMM2's epilogue (after it). Barrier-separated.
    unsigned* sMu = (unsigned*)sMsg;

    const int tid  = threadIdx.x;
    const int hb   = blockIdx.x & 1;
    const int bseq = blockIdx.x >> 1;            // 0..511

    // ---- stage W1 half (fp32 -> packed bf16 pairs; stride 97 uints) ----
    for (int i = tid; i < 128 * 96; i += 256) {
        int r = i / 96, c2 = i - r * 96;
        const float* wr = W1 + (hb * 128 + r) * 192 + c2 * 2;
        sW1u[r * 97 + c2] = (unsigned)f2bf(wr[0]) | ((unsigned)f2bf(wr[1]) << 16);
    }
    if (tid < 128) sB1[tid] = b1[hb * 128 + tid];

    const int o    = tid & 127;
    const int lane = tid & 63;
    const int e16  = lane & 15;
    const int q    = lane >> 4;
    const int wv   = tid >> 6;

    // ---- W2 half as register-resident MFMA A-fragments ----
    // Wave wv owns out-tiles ot = wv*2 + {0,1}. A-fragment rule (same as
    // GEMM1, verified): lane(e16,q) holds A[row=e16][k = kb*32 + q*8 + j].
    bf16x8 w2frag[2][4];
    #pragma unroll
    for (int mtl = 0; mtl < 2; ++mtl) {
        const float* wbase = W2 + (size_t)((wv * 2 + mtl) * 16 + e16) * 256 + hb * 128 + q * 8;
        #pragma unroll
        for (int kb = 0; kb < 4; ++kb) {
            const float* wr = wbase + kb * 32;
            int4 ai;
            ai.x = (int)((unsigned)f2bf(wr[0]) | ((unsigned)f2bf(wr[1]) << 16));
            ai.y = (int)((unsigned)f2bf(wr[2]) | ((unsigned)f2bf(wr[3]) << 16));
            ai.z = (int)((unsigned)f2bf(wr[4]) | ((unsigned)f2bf(wr[5]) << 16));
            ai.w = (int)((unsigned)f2bf(wr[6]) | ((unsigned)f2bf(wr[7]) << 16));
            w2frag[mtl][kb] = __builtin_bit_cast(bf16x8, ai);
        }
    }
    const float b2o = (hb == 0) ? b2[o] : 0.f;

    __syncthreads();

    for (int g = bseq; g < 40000; g += 512) {
        if (tid < 16) {
            sSE[tid] = ei[g * 16 + tid];
            sDE[tid] = ei[N_EDGES + g * 16 + tid];
        }
        __syncthreads();

        // ---- stage m = concat(x[src], edge_attr) as bf16 pairs (float4 loads) ----
        for (int i = tid; i < 16 * 48; i += 256) {
            int ee = i / 48, c4 = i - ee * 48;
            int k = c4 * 4;
            float4 v;
            if (k < 128) v = *(const float4*)(x + (size_t)sSE[ee] * 128 + k);
            else         v = *(const float4*)(ea + (size_t)(g * 16 + ee) * 64 + (k - 128));
            unsigned* mp = sMu + ee * 97 + c4 * 2;
            mp[0] = (unsigned)f2bf(v.x) | ((unsigned)f2bf(v.y) << 16);
            mp[1] = (unsigned)f2bf(v.z) | ((unsigned)f2bf(v.w) << 16);
        }
        __syncthreads();

        // ---- GEMM1 (MFMA): wave wv computes hid tiles mt = wv*2+{0,1} ----
        // D: col=e16 (edge), row=q*4+r (hid within tile)  [verified m89/m91/m120]
        {
            f32x4 acc[2];
            acc[0] = (f32x4){0.f, 0.f, 0.f, 0.f};
            acc[1] = (f32x4){0.f, 0.f, 0.f, 0.f};
            #pragma unroll
            for (int ks = 0; ks < 6; ++ks) {
                const unsigned* mp = sMu + e16 * 97 + ks * 16 + q * 4;
                int4 bi;
                bi.x = (int)mp[0]; bi.y = (int)mp[1];
                bi.z = (int)mp[2]; bi.w = (int)mp[3];
                bf16x8 bfrag = __builtin_bit_cast(bf16x8, bi);
                #pragma unroll
                for (int mtl = 0; mtl < 2; ++mtl) {
                    const unsigned* ap = sW1u + ((wv * 2 + mtl) * 16 + e16) * 97 + ks * 16 + q * 4;
                    int4 ai;
                    ai.x = (int)ap[0]; ai.y = (int)ap[1];
                    ai.z = (int)ap[2]; ai.w = (int)ap[3];
                    bf16x8 afrag = __builtin_bit_cast(bf16x8, ai);
                    acc[mtl] = __builtin_amdgcn_mfma_f32_16x16x32_bf16(afrag, bfrag, acc[mtl], 0, 0, 0);
                }
            }
            #pragma unroll
            for (int mtl = 0; mtl < 2; ++mtl) {
                const int hid = (wv * 2 + mtl) * 16 + q * 4;
                float v0 = fmaxf(acc[mtl][0] + sB1[hid + 0], 0.f);
                float v1 = fmaxf(acc[mtl][1] + sB1[hid + 1], 0.f);
                float v2 = fmaxf(acc[mtl][2] + sB1[hid + 2], 0.f);
                float v3 = fmaxf(acc[mtl][3] + sB1[hid + 3], 0.f);
                unsigned* hp = ((unsigned*)sHu) + e16 * 66 + (hid >> 1);
                hp[0] = (unsigned)f2bf(v0) | ((unsigned)f2bf(v1) << 16);
                hp[1] = (unsigned)f2bf(v2) | ((unsigned)f2bf(v3) << 16);
            }
        }
        __syncthreads();

        // ---- GEMM2 (MFMA): wave wv computes out tiles ot = wv*2+{0,1} ----
        // B[k][n=e16] = h[e16][k] straight from sHu (same packing rule as sMu).
        // D: col=e16 (edge), row=q*4+r (out within tile) -> sMsg.
        {
            f32x4 acc2[2];
            acc2[0] = (f32x4){0.f, 0.f, 0.f, 0.f};
            acc2[1] = (f32x4){0.f, 0.f, 0.f, 0.f};
            #pragma unroll
            for (int kb = 0; kb < 4; ++kb) {
                const unsigned* hp = ((const unsigned*)sHu) + e16 * 66 + kb * 16 + q * 4;
                int4 bi;
                bi.x = (int)hp[0]; bi.y = (int)hp[1];
                bi.z = (int)hp[2]; bi.w = (int)hp[3];
                bf16x8 bfrag = __builtin_bit_cast(bf16x8, bi);
                acc2[0] = __builtin_amdgcn_mfma_f32_16x16x32_bf16(w2frag[0][kb], bfrag, acc2[0], 0, 0, 0);
                acc2[1] = __builtin_amdgcn_mfma_f32_16x16x32_bf16(w2frag[1][kb], bfrag, acc2[1], 0, 0, 0);
            }
            #pragma unroll
            for (int mtl = 0; mtl < 2; ++mtl) {
                float* mp = sMsg + e16 * 132 + (wv * 2 + mtl) * 16 + q * 4;
                mp[0] = acc2[mtl][0]; mp[1] = acc2[mtl][1];
                mp[2] = acc2[mtl][2]; mp[3] = acc2[mtl][3];
            }
        }
        __syncthreads();

        // ---- coalesced scatter (unchanged structure) ----
        {
            const int eb = (tid >> 7) * 8;
            #pragma unroll
            for (int q2 = 0; q2 < 8; ++q2) {
                int ee = eb + q2;
                float v = sMsg[ee * 132 + o] + b2o;
                unsafeAtomicAdd(out + (size_t)sDE[ee] * 128 + o, v);
            }
        }
        __syncthreads();
    }
}

extern "C" void kernel_launch(void* const* d_in, const int* in_sizes, int n_in,
                              void* d_out, int out_size, void* d_ws, size_t ws_size,
                              hipStream_t stream) {
    const float* x  = (const float*)d_in[0];
    const int*   ei = (const int*)d_in[1];
    const float* ea = (const float*)d_in[2];
    const float* W1 = (const float*)d_in[3];
    const float* b1 = (const float*)d_in[4];
    const float* W2 = (const float*)d_in[5];
    const float* b2 = (const float*)d_in[6];
    float* out = (float*)d_out;

    zero_kernel<<<1250, 256, 0, stream>>>(out);
    gine_hybrid<<<1024, 256, 0, stream>>>(ei, x, ea, W1, b1, W2, b2, out);
}